// Round 14
// baseline (943.229 us; speedup 1.0000x reference)
//
#include <hip/hip_runtime.h>

// GCN autoencoder — R14 MEASUREMENT ROUND.
// Pipeline = EXACT R13 (194 us). Launch sequence amplified:
//   K1 x16 (gemm+zero cursor; all pre-scatter, idempotent)
//   K2 x1  (scatter; not idempotent)
//   K3 x16 (spmm1_mlp; idempotent)
//   K4 x16 (spmm2; idempotent)
//   zzt x1
// With OH~0 (R6+R7 joint), S = K1+K3+K4 = (dur-194)/15 exactly.
// Branch A (physics): S~13-25 -> dur 390-570 -> Z~170, front small ->
//   R15 attacks zzt stores. Branch B: S~90 -> dur ~1.5ms and the heavy
//   kernel appears in top-5 WITH counters.

constexpr int N_   = 10000;
constexpr int E_   = 320000;
constexpr int F_   = 512;
constexpr int H1_  = 32;
constexpr int H2_  = 16;
constexpr int CAP_ = 96;   // ELL row capacity; P[Poisson(32) > 96] ~ 3e-20

typedef float f32x4 __attribute__((ext_vector_type(4)));

// ---------------- K1: h = X @ W1 (4 cols/thread), side blocks zero cursor --
constexpr int GEMM_THREADS = N_ * (H1_ / 4);            // 80000
constexpr int GEMM_BLOCKS  = (GEMM_THREADS + 255) / 256; // 313
constexpr int ZERO_BLOCKS  = (N_ + 255) / 256;           // 40

__global__ __launch_bounds__(256) void gemm_xw1_zero(const float* __restrict__ x,
                                                     const float* __restrict__ W1,
                                                     float* __restrict__ h,
                                                     int* __restrict__ cursor) {
    if (blockIdx.x >= GEMM_BLOCKS) {
        int i = (blockIdx.x - GEMM_BLOCKS) * 256 + threadIdx.x;
        if (i < N_) cursor[i] = 0;
        return;
    }
    int tid = blockIdx.x * blockDim.x + threadIdx.x;
    if (tid >= GEMM_THREADS) return;
    int r  = tid >> 3;              // /8
    int cq = (tid & 7) * 4;         // column quad 0,4,...,28
    const float4* xr = reinterpret_cast<const float4*>(x + (size_t)r * F_);
    float4 acc = make_float4(0.f, 0.f, 0.f, 0.f);
#pragma unroll 4
    for (int k4 = 0; k4 < F_ / 4; ++k4) {
        float4 xv = xr[k4];
        int k = k4 * 4;
        float4 w0 = *reinterpret_cast<const float4*>(W1 + (k + 0) * H1_ + cq);
        float4 w1 = *reinterpret_cast<const float4*>(W1 + (k + 1) * H1_ + cq);
        float4 w2 = *reinterpret_cast<const float4*>(W1 + (k + 2) * H1_ + cq);
        float4 w3 = *reinterpret_cast<const float4*>(W1 + (k + 3) * H1_ + cq);
        acc.x = fmaf(xv.x, w0.x, acc.x); acc.y = fmaf(xv.x, w0.y, acc.y);
        acc.z = fmaf(xv.x, w0.z, acc.z); acc.w = fmaf(xv.x, w0.w, acc.w);
        acc.x = fmaf(xv.y, w1.x, acc.x); acc.y = fmaf(xv.y, w1.y, acc.y);
        acc.z = fmaf(xv.y, w1.z, acc.z); acc.w = fmaf(xv.y, w1.w, acc.w);
        acc.x = fmaf(xv.z, w2.x, acc.x); acc.y = fmaf(xv.z, w2.y, acc.y);
        acc.z = fmaf(xv.z, w2.z, acc.z); acc.w = fmaf(xv.z, w2.w, acc.w);
        acc.x = fmaf(xv.w, w3.x, acc.x); acc.y = fmaf(xv.w, w3.y, acc.y);
        acc.z = fmaf(xv.w, w3.z, acc.z); acc.w = fmaf(xv.w, w3.w, acc.w);
    }
    *reinterpret_cast<float4*>(h + (size_t)r * H1_ + cq) = acc;
}

// ---------------- K2: scatter edges into ELL rows ----------------
__global__ __launch_bounds__(256) void scatter_ell(const int* __restrict__ erow,
                                                   const int* __restrict__ ecol,
                                                   const float* __restrict__ ew,
                                                   int* __restrict__ cursor,
                                                   int* __restrict__ cole,
                                                   float* __restrict__ we) {
    int e = blockIdx.x * blockDim.x + threadIdx.x;
    if (e >= E_) return;
    int r = erow[e];
    int p = atomicAdd(&cursor[r], 1);
    if (p < CAP_) {                       // overflow-impossible guard
        size_t idx = (size_t)r * CAP_ + p;
        cole[idx] = ecol[e];
        we[idx]   = ew[e];
    }
}

// ---------------- K3: h2 = relu(A @ h) @ W2  (8 rows / block) --------------
__global__ __launch_bounds__(256) void spmm1_mlp(const float* __restrict__ h,
                                                 const int* __restrict__ cursor,
                                                 const int* __restrict__ cole,
                                                 const float* __restrict__ we,
                                                 const float* __restrict__ W2,
                                                 float* __restrict__ h2) {
    __shared__ float sh1[8][H1_ + 1];
    __shared__ float sW2[H1_ * H2_];
    const int t = threadIdx.x;
    sW2[t]       = W2[t];
    sW2[t + 256] = W2[t + 256];

    const int rl = t >> 5;           // 0..7
    const int f  = t & (H1_ - 1);
    const int r  = blockIdx.x * 8 + rl;
    float acc = 0.f;
    if (r < N_) {
        const int deg = cursor[r];
        const int*   cp = cole + (size_t)r * CAP_;   // 384B-aligned
        const float* wp = we   + (size_t)r * CAP_;
        int p = 0;
        for (; p + 8 <= deg; p += 8) {
            int4   c0 = *reinterpret_cast<const int4*>(cp + p);
            int4   c1 = *reinterpret_cast<const int4*>(cp + p + 4);
            float4 w0 = *reinterpret_cast<const float4*>(wp + p);
            float4 w1 = *reinterpret_cast<const float4*>(wp + p + 4);
            float g0 = h[(size_t)c0.x * H1_ + f];
            float g1 = h[(size_t)c0.y * H1_ + f];
            float g2 = h[(size_t)c0.z * H1_ + f];
            float g3 = h[(size_t)c0.w * H1_ + f];
            float g4 = h[(size_t)c1.x * H1_ + f];
            float g5 = h[(size_t)c1.y * H1_ + f];
            float g6 = h[(size_t)c1.z * H1_ + f];
            float g7 = h[(size_t)c1.w * H1_ + f];
            acc = fmaf(w0.x, g0, acc);
            acc = fmaf(w0.y, g1, acc);
            acc = fmaf(w0.z, g2, acc);
            acc = fmaf(w0.w, g3, acc);
            acc = fmaf(w1.x, g4, acc);
            acc = fmaf(w1.y, g5, acc);
            acc = fmaf(w1.z, g6, acc);
            acc = fmaf(w1.w, g7, acc);
        }
        for (; p < deg; ++p)
            acc = fmaf(wp[p], h[(size_t)cp[p] * H1_ + f], acc);
    }
    sh1[rl][f] = fmaxf(acc, 0.f);     // relu fused here
    __syncthreads();

    if (t < 128) {
        const int r2l = t >> 4;       // 0..7
        const int c   = t & (H2_ - 1);
        const int r2  = blockIdx.x * 8 + r2l;
        if (r2 < N_) {
            float a = 0.f;
#pragma unroll
            for (int k = 0; k < H1_; ++k)
                a = fmaf(sh1[r2l][k], sW2[k * H2_ + c], a);
            h2[(size_t)r2 * H2_ + c] = a;
        }
    }
}

// ---------------- K4: z = A @ h2  (16 rows / block) ----------------
__global__ __launch_bounds__(256) void spmm2(const float* __restrict__ h2,
                                             const int* __restrict__ cursor,
                                             const int* __restrict__ cole,
                                             const float* __restrict__ we,
                                             float* __restrict__ z) {
    const int t = threadIdx.x;
    const int rl = t >> 4;            // 0..15
    const int f  = t & (H2_ - 1);
    const int r  = blockIdx.x * 16 + rl;
    if (r >= N_) return;
    const int deg = cursor[r];
    const int*   cp = cole + (size_t)r * CAP_;
    const float* wp = we   + (size_t)r * CAP_;
    float acc = 0.f;
    int p = 0;
    for (; p + 8 <= deg; p += 8) {
        int4   c0 = *reinterpret_cast<const int4*>(cp + p);
        int4   c1 = *reinterpret_cast<const int4*>(cp + p + 4);
        float4 w0 = *reinterpret_cast<const float4*>(wp + p);
        float4 w1 = *reinterpret_cast<const float4*>(wp + p + 4);
        float g0 = h2[(size_t)c0.x * H2_ + f];
        float g1 = h2[(size_t)c0.y * H2_ + f];
        float g2 = h2[(size_t)c0.z * H2_ + f];
        float g3 = h2[(size_t)c0.w * H2_ + f];
        float g4 = h2[(size_t)c1.x * H2_ + f];
        float g5 = h2[(size_t)c1.y * H2_ + f];
        float g6 = h2[(size_t)c1.z * H2_ + f];
        float g7 = h2[(size_t)c1.w * H2_ + f];
        acc = fmaf(w0.x, g0, acc);
        acc = fmaf(w0.y, g1, acc);
        acc = fmaf(w0.z, g2, acc);
        acc = fmaf(w0.w, g3, acc);
        acc = fmaf(w1.x, g4, acc);
        acc = fmaf(w1.y, g5, acc);
        acc = fmaf(w1.z, g6, acc);
        acc = fmaf(w1.w, g7, acc);
    }
    for (; p < deg; ++p)
        acc = fmaf(wp[p], h2[(size_t)cp[p] * H2_ + f], acc);
    z[(size_t)r * H2_ + f] = acc;
}

// ---------------- K5: out = z @ z^T  (EXACT R10: 64x256, 8x8/thread) -------
constexpr int BI = 64;
constexpr int BJ = 256;

__global__ __launch_bounds__(256) void zzt(const float* __restrict__ z,
                                           float* __restrict__ out) {
    __shared__ float zi[H2_][BI + 4];    // 16 x 68
    __shared__ float zj[H2_][BJ + 8];    // 16 x 264
    const int t  = threadIdx.x;
    const int ib = blockIdx.y * BI;
    const int jb = blockIdx.x * BJ;

    {
        int row = t >> 2;
        int kq  = (t & 3) * 4;
        int gr  = ib + row;
        float4 v = (gr < N_)
            ? *reinterpret_cast<const float4*>(z + (size_t)gr * H2_ + kq)
            : make_float4(0.f, 0.f, 0.f, 0.f);
        zi[kq + 0][row] = v.x;
        zi[kq + 1][row] = v.y;
        zi[kq + 2][row] = v.z;
        zi[kq + 3][row] = v.w;
    }
#pragma unroll
    for (int it = 0; it < 4; ++it) {
        int idx = it * 256 + t;
        int row = idx >> 2;
        int kq  = (idx & 3) * 4;
        int gr  = jb + row;
        float4 v = (gr < N_)
            ? *reinterpret_cast<const float4*>(z + (size_t)gr * H2_ + kq)
            : make_float4(0.f, 0.f, 0.f, 0.f);
        zj[kq + 0][row] = v.x;
        zj[kq + 1][row] = v.y;
        zj[kq + 2][row] = v.z;
        zj[kq + 3][row] = v.w;
    }
    __syncthreads();

    const int tj = t & 31;          // 32 j-lanes
    const int i0 = (t >> 5) * 8;    // 8 i-groups of 8 rows

    float4 accA[8] = {};            // j = jb + tj*4 .. +3
    float4 accB[8] = {};            // j = jb + 128 + tj*4 .. +3

#pragma unroll
    for (int k = 0; k < H2_; ++k) {
        float4 b0 = *reinterpret_cast<const float4*>(&zj[k][tj * 4]);
        float4 b1 = *reinterpret_cast<const float4*>(&zj[k][128 + tj * 4]);
        float4 a0 = *reinterpret_cast<const float4*>(&zi[k][i0]);      // bcast
        float4 a1 = *reinterpret_cast<const float4*>(&zi[k][i0 + 4]);  // bcast
        float av[8] = {a0.x, a0.y, a0.z, a0.w, a1.x, a1.y, a1.z, a1.w};
#pragma unroll
        for (int ii = 0; ii < 8; ++ii) {
            accA[ii].x = fmaf(av[ii], b0.x, accA[ii].x);
            accA[ii].y = fmaf(av[ii], b0.y, accA[ii].y);
            accA[ii].z = fmaf(av[ii], b0.z, accA[ii].z);
            accA[ii].w = fmaf(av[ii], b0.w, accA[ii].w);
            accB[ii].x = fmaf(av[ii], b1.x, accB[ii].x);
            accB[ii].y = fmaf(av[ii], b1.y, accB[ii].y);
            accB[ii].z = fmaf(av[ii], b1.z, accB[ii].z);
            accB[ii].w = fmaf(av[ii], b1.w, accB[ii].w);
        }
    }

    const int j0 = jb + tj * 4;
    const int j1 = jb + 128 + tj * 4;
#pragma unroll
    for (int ii = 0; ii < 8; ++ii) {
        int gi = ib + i0 + ii;
        if (gi >= N_) break;
        float* orow = out + (size_t)gi * N_;
        if (j0 + 3 < N_) {
            f32x4 v = {accA[ii].x, accA[ii].y, accA[ii].z, accA[ii].w};
            __builtin_nontemporal_store(v, reinterpret_cast<f32x4*>(orow + j0));
        } else {
            float a[4] = {accA[ii].x, accA[ii].y, accA[ii].z, accA[ii].w};
            for (int jj = 0; jj < 4; ++jj)
                if (j0 + jj < N_) orow[j0 + jj] = a[jj];
        }
        if (j1 + 3 < N_) {
            f32x4 v = {accB[ii].x, accB[ii].y, accB[ii].z, accB[ii].w};
            __builtin_nontemporal_store(v, reinterpret_cast<f32x4*>(orow + j1));
        } else {
            float b[4] = {accB[ii].x, accB[ii].y, accB[ii].z, accB[ii].w};
            for (int jj = 0; jj < 4; ++jj)
                if (j1 + jj < N_) orow[j1 + jj] = b[jj];
        }
    }
}

extern "C" void kernel_launch(void* const* d_in, const int* in_sizes, int n_in,
                              void* d_out, int out_size, void* d_ws, size_t ws_size,
                              hipStream_t stream) {
    const float* x    = (const float*)d_in[0];
    const float* ew   = (const float*)d_in[1];
    const float* W1   = (const float*)d_in[2];
    const float* W2   = (const float*)d_in[3];
    const int*   erow = (const int*)d_in[4];
    const int*   ecol = (const int*)d_in[5];
    float* out = (float*)d_out;

    // workspace layout (4B elements) — same as R13
    float* h      = (float*)d_ws;              // N*H1
    float* h2     = h  + (size_t)N_ * H1_;     // N*H2
    float* z      = h2 + (size_t)N_ * H2_;     // N*H2
    float* we     = z  + (size_t)N_ * H2_;     // N*CAP
    int*   cole   = (int*)(we + (size_t)N_ * CAP_);   // N*CAP
    int*   cursor = cole + (size_t)N_ * CAP_;  // N

    constexpr int REP = 16;

    // K1 x16: all BEFORE scatter (cursor re-zeroed each time; h idempotent)
    for (int i = 0; i < REP; ++i)
        gemm_xw1_zero<<<GEMM_BLOCKS + ZERO_BLOCKS, 256, 0, stream>>>(x, W1, h, cursor);
    // K2 x1 (not idempotent)
    scatter_ell<<<(E_ + 255) / 256, 256, 0, stream>>>(erow, ecol, ew, cursor, cole, we);
    // K3 x16 (idempotent)
    for (int i = 0; i < REP; ++i)
        spmm1_mlp<<<(N_ + 7) / 8, 256, 0, stream>>>(h, cursor, cole, we, W2, h2);
    // K4 x16 (idempotent)
    for (int i = 0; i < REP; ++i)
        spmm2<<<(N_ + 15) / 16, 256, 0, stream>>>(h2, cursor, cole, we, z);

    dim3 grid((N_ + BJ - 1) / BJ, (N_ + BI - 1) / BI);   // 40 x 157
    zzt<<<grid, 256, 0, stream>>>(z, out);
}

// Round 15
// 283.712 us; speedup vs baseline: 3.3246x; 3.3246x over previous
//
#include <hip/hip_runtime.h>

// GCN autoencoder — R15 DIAGNOSTIC ROUND (counters for zzt at last).
// Pipeline = EXACT R13 (194 us; front ~58 measured by R14's x16 amplify,
// zzt ~136 = 2.9 TB/s effective write BW vs fill kernel's 6.9 on the SAME
// buffer). The top-5 profile is sorted by dur and clogged by ~230us harness
// fills, so zzt never shows counters. Fix: zzt body looped x2 inside ONE
// dispatch (idempotent; same-value cross-wave staging races are benign;
// syncthreads at rep boundary). That dispatch ~275us -> top-1 WITH PMCs.
// Decision table pre-committed in journal: WRITE_SIZE/hbm_gbps/VALUBusy/
// Occupancy/LDS_CONFLICT each select a different R16.

constexpr int N_   = 10000;
constexpr int E_   = 320000;
constexpr int F_   = 512;
constexpr int H1_  = 32;
constexpr int H2_  = 16;
constexpr int CAP_ = 96;   // ELL row capacity; P[Poisson(32) > 96] ~ 3e-20

typedef float f32x4 __attribute__((ext_vector_type(4)));

// ---------------- K1: h = X @ W1 (4 cols/thread), side blocks zero cursor --
constexpr int GEMM_THREADS = N_ * (H1_ / 4);            // 80000
constexpr int GEMM_BLOCKS  = (GEMM_THREADS + 255) / 256; // 313
constexpr int ZERO_BLOCKS  = (N_ + 255) / 256;           // 40

__global__ __launch_bounds__(256) void gemm_xw1_zero(const float* __restrict__ x,
                                                     const float* __restrict__ W1,
                                                     float* __restrict__ h,
                                                     int* __restrict__ cursor) {
    if (blockIdx.x >= GEMM_BLOCKS) {
        int i = (blockIdx.x - GEMM_BLOCKS) * 256 + threadIdx.x;
        if (i < N_) cursor[i] = 0;
        return;
    }
    int tid = blockIdx.x * blockDim.x + threadIdx.x;
    if (tid >= GEMM_THREADS) return;
    int r  = tid >> 3;              // /8
    int cq = (tid & 7) * 4;         // column quad 0,4,...,28
    const float4* xr = reinterpret_cast<const float4*>(x + (size_t)r * F_);
    float4 acc = make_float4(0.f, 0.f, 0.f, 0.f);
#pragma unroll 4
    for (int k4 = 0; k4 < F_ / 4; ++k4) {
        float4 xv = xr[k4];
        int k = k4 * 4;
        float4 w0 = *reinterpret_cast<const float4*>(W1 + (k + 0) * H1_ + cq);
        float4 w1 = *reinterpret_cast<const float4*>(W1 + (k + 1) * H1_ + cq);
        float4 w2 = *reinterpret_cast<const float4*>(W1 + (k + 2) * H1_ + cq);
        float4 w3 = *reinterpret_cast<const float4*>(W1 + (k + 3) * H1_ + cq);
        acc.x = fmaf(xv.x, w0.x, acc.x); acc.y = fmaf(xv.x, w0.y, acc.y);
        acc.z = fmaf(xv.x, w0.z, acc.z); acc.w = fmaf(xv.x, w0.w, acc.w);
        acc.x = fmaf(xv.y, w1.x, acc.x); acc.y = fmaf(xv.y, w1.y, acc.y);
        acc.z = fmaf(xv.y, w1.z, acc.z); acc.w = fmaf(xv.y, w1.w, acc.w);
        acc.x = fmaf(xv.z, w2.x, acc.x); acc.y = fmaf(xv.z, w2.y, acc.y);
        acc.z = fmaf(xv.z, w2.z, acc.z); acc.w = fmaf(xv.z, w2.w, acc.w);
        acc.x = fmaf(xv.w, w3.x, acc.x); acc.y = fmaf(xv.w, w3.y, acc.y);
        acc.z = fmaf(xv.w, w3.z, acc.z); acc.w = fmaf(xv.w, w3.w, acc.w);
    }
    *reinterpret_cast<float4*>(h + (size_t)r * H1_ + cq) = acc;
}

// ---------------- K2: scatter edges into ELL rows ----------------
__global__ __launch_bounds__(256) void scatter_ell(const int* __restrict__ erow,
                                                   const int* __restrict__ ecol,
                                                   const float* __restrict__ ew,
                                                   int* __restrict__ cursor,
                                                   int* __restrict__ cole,
                                                   float* __restrict__ we) {
    int e = blockIdx.x * blockDim.x + threadIdx.x;
    if (e >= E_) return;
    int r = erow[e];
    int p = atomicAdd(&cursor[r], 1);
    if (p < CAP_) {                       // overflow-impossible guard
        size_t idx = (size_t)r * CAP_ + p;
        cole[idx] = ecol[e];
        we[idx]   = ew[e];
    }
}

// ---------------- K3: h2 = relu(A @ h) @ W2  (8 rows / block) --------------
__global__ __launch_bounds__(256) void spmm1_mlp(const float* __restrict__ h,
                                                 const int* __restrict__ cursor,
                                                 const int* __restrict__ cole,
                                                 const float* __restrict__ we,
                                                 const float* __restrict__ W2,
                                                 float* __restrict__ h2) {
    __shared__ float sh1[8][H1_ + 1];
    __shared__ float sW2[H1_ * H2_];
    const int t = threadIdx.x;
    sW2[t]       = W2[t];
    sW2[t + 256] = W2[t + 256];

    const int rl = t >> 5;           // 0..7
    const int f  = t & (H1_ - 1);
    const int r  = blockIdx.x * 8 + rl;
    float acc = 0.f;
    if (r < N_) {
        const int deg = cursor[r];
        const int*   cp = cole + (size_t)r * CAP_;   // 384B-aligned
        const float* wp = we   + (size_t)r * CAP_;
        int p = 0;
        for (; p + 8 <= deg; p += 8) {
            int4   c0 = *reinterpret_cast<const int4*>(cp + p);
            int4   c1 = *reinterpret_cast<const int4*>(cp + p + 4);
            float4 w0 = *reinterpret_cast<const float4*>(wp + p);
            float4 w1 = *reinterpret_cast<const float4*>(wp + p + 4);
            float g0 = h[(size_t)c0.x * H1_ + f];
            float g1 = h[(size_t)c0.y * H1_ + f];
            float g2 = h[(size_t)c0.z * H1_ + f];
            float g3 = h[(size_t)c0.w * H1_ + f];
            float g4 = h[(size_t)c1.x * H1_ + f];
            float g5 = h[(size_t)c1.y * H1_ + f];
            float g6 = h[(size_t)c1.z * H1_ + f];
            float g7 = h[(size_t)c1.w * H1_ + f];
            acc = fmaf(w0.x, g0, acc);
            acc = fmaf(w0.y, g1, acc);
            acc = fmaf(w0.z, g2, acc);
            acc = fmaf(w0.w, g3, acc);
            acc = fmaf(w1.x, g4, acc);
            acc = fmaf(w1.y, g5, acc);
            acc = fmaf(w1.z, g6, acc);
            acc = fmaf(w1.w, g7, acc);
        }
        for (; p < deg; ++p)
            acc = fmaf(wp[p], h[(size_t)cp[p] * H1_ + f], acc);
    }
    sh1[rl][f] = fmaxf(acc, 0.f);     // relu fused here
    __syncthreads();

    if (t < 128) {
        const int r2l = t >> 4;       // 0..7
        const int c   = t & (H2_ - 1);
        const int r2  = blockIdx.x * 8 + r2l;
        if (r2 < N_) {
            float a = 0.f;
#pragma unroll
            for (int k = 0; k < H1_; ++k)
                a = fmaf(sh1[r2l][k], sW2[k * H2_ + c], a);
            h2[(size_t)r2 * H2_ + c] = a;
        }
    }
}

// ---------------- K4: z = A @ h2  (16 rows / block) ----------------
__global__ __launch_bounds__(256) void spmm2(const float* __restrict__ h2,
                                             const int* __restrict__ cursor,
                                             const int* __restrict__ cole,
                                             const float* __restrict__ we,
                                             float* __restrict__ z) {
    const int t = threadIdx.x;
    const int rl = t >> 4;            // 0..15
    const int f  = t & (H2_ - 1);
    const int r  = blockIdx.x * 16 + rl;
    if (r >= N_) return;
    const int deg = cursor[r];
    const int*   cp = cole + (size_t)r * CAP_;
    const float* wp = we   + (size_t)r * CAP_;
    float acc = 0.f;
    int p = 0;
    for (; p + 8 <= deg; p += 8) {
        int4   c0 = *reinterpret_cast<const int4*>(cp + p);
        int4   c1 = *reinterpret_cast<const int4*>(cp + p + 4);
        float4 w0 = *reinterpret_cast<const float4*>(wp + p);
        float4 w1 = *reinterpret_cast<const float4*>(wp + p + 4);
        float g0 = h2[(size_t)c0.x * H2_ + f];
        float g1 = h2[(size_t)c0.y * H2_ + f];
        float g2 = h2[(size_t)c0.z * H2_ + f];
        float g3 = h2[(size_t)c0.w * H2_ + f];
        float g4 = h2[(size_t)c1.x * H2_ + f];
        float g5 = h2[(size_t)c1.y * H2_ + f];
        float g6 = h2[(size_t)c1.z * H2_ + f];
        float g7 = h2[(size_t)c1.w * H2_ + f];
        acc = fmaf(w0.x, g0, acc);
        acc = fmaf(w0.y, g1, acc);
        acc = fmaf(w0.z, g2, acc);
        acc = fmaf(w0.w, g3, acc);
        acc = fmaf(w1.x, g4, acc);
        acc = fmaf(w1.y, g5, acc);
        acc = fmaf(w1.z, g6, acc);
        acc = fmaf(w1.w, g7, acc);
    }
    for (; p < deg; ++p)
        acc = fmaf(wp[p], h2[(size_t)cp[p] * H2_ + f], acc);
    z[(size_t)r * H2_ + f] = acc;
}

// ---------------- K5: out = z @ z^T  (R10 body, REPEATED x2 in-kernel) -----
constexpr int BI = 64;
constexpr int BJ = 256;

__global__ __launch_bounds__(256) void zzt2x(const float* __restrict__ z,
                                             float* __restrict__ out) {
    __shared__ float zi[H2_][BI + 4];    // 16 x 68
    __shared__ float zj[H2_][BJ + 8];    // 16 x 264
    const int t  = threadIdx.x;
    const int ib = blockIdx.y * BI;
    const int jb = blockIdx.x * BJ;

    for (int rep = 0; rep < 2; ++rep) {
        __syncthreads();   // rep boundary (first iter: harmless)

        {
            int row = t >> 2;
            int kq  = (t & 3) * 4;
            int gr  = ib + row;
            float4 v = (gr < N_)
                ? *reinterpret_cast<const float4*>(z + (size_t)gr * H2_ + kq)
                : make_float4(0.f, 0.f, 0.f, 0.f);
            zi[kq + 0][row] = v.x;
            zi[kq + 1][row] = v.y;
            zi[kq + 2][row] = v.z;
            zi[kq + 3][row] = v.w;
        }
#pragma unroll
        for (int it = 0; it < 4; ++it) {
            int idx = it * 256 + t;
            int row = idx >> 2;
            int kq  = (idx & 3) * 4;
            int gr  = jb + row;
            float4 v = (gr < N_)
                ? *reinterpret_cast<const float4*>(z + (size_t)gr * H2_ + kq)
                : make_float4(0.f, 0.f, 0.f, 0.f);
            zj[kq + 0][row] = v.x;
            zj[kq + 1][row] = v.y;
            zj[kq + 2][row] = v.z;
            zj[kq + 3][row] = v.w;
        }
        __syncthreads();

        const int tj = t & 31;          // 32 j-lanes
        const int i0 = (t >> 5) * 8;    // 8 i-groups of 8 rows

        float4 accA[8] = {};            // j = jb + tj*4 .. +3
        float4 accB[8] = {};            // j = jb + 128 + tj*4 .. +3

#pragma unroll
        for (int k = 0; k < H2_; ++k) {
            float4 b0 = *reinterpret_cast<const float4*>(&zj[k][tj * 4]);
            float4 b1 = *reinterpret_cast<const float4*>(&zj[k][128 + tj * 4]);
            float4 a0 = *reinterpret_cast<const float4*>(&zi[k][i0]);      // bcast
            float4 a1 = *reinterpret_cast<const float4*>(&zi[k][i0 + 4]);  // bcast
            float av[8] = {a0.x, a0.y, a0.z, a0.w, a1.x, a1.y, a1.z, a1.w};
#pragma unroll
            for (int ii = 0; ii < 8; ++ii) {
                accA[ii].x = fmaf(av[ii], b0.x, accA[ii].x);
                accA[ii].y = fmaf(av[ii], b0.y, accA[ii].y);
                accA[ii].z = fmaf(av[ii], b0.z, accA[ii].z);
                accA[ii].w = fmaf(av[ii], b0.w, accA[ii].w);
                accB[ii].x = fmaf(av[ii], b1.x, accB[ii].x);
                accB[ii].y = fmaf(av[ii], b1.y, accB[ii].y);
                accB[ii].z = fmaf(av[ii], b1.z, accB[ii].z);
                accB[ii].w = fmaf(av[ii], b1.w, accB[ii].w);
            }
        }

        const int j0 = jb + tj * 4;
        const int j1 = jb + 128 + tj * 4;
#pragma unroll
        for (int ii = 0; ii < 8; ++ii) {
            int gi = ib + i0 + ii;
            if (gi >= N_) break;
            float* orow = out + (size_t)gi * N_;
            if (j0 + 3 < N_) {
                f32x4 v = {accA[ii].x, accA[ii].y, accA[ii].z, accA[ii].w};
                __builtin_nontemporal_store(v, reinterpret_cast<f32x4*>(orow + j0));
            } else {
                float a[4] = {accA[ii].x, accA[ii].y, accA[ii].z, accA[ii].w};
                for (int jj = 0; jj < 4; ++jj)
                    if (j0 + jj < N_) orow[j0 + jj] = a[jj];
            }
            if (j1 + 3 < N_) {
                f32x4 v = {accB[ii].x, accB[ii].y, accB[ii].z, accB[ii].w};
                __builtin_nontemporal_store(v, reinterpret_cast<f32x4*>(orow + j1));
            } else {
                float b[4] = {accB[ii].x, accB[ii].y, accB[ii].z, accB[ii].w};
                for (int jj = 0; jj < 4; ++jj)
                    if (j1 + jj < N_) orow[j1 + jj] = b[jj];
            }
        }
    }
}

extern "C" void kernel_launch(void* const* d_in, const int* in_sizes, int n_in,
                              void* d_out, int out_size, void* d_ws, size_t ws_size,
                              hipStream_t stream) {
    const float* x    = (const float*)d_in[0];
    const float* ew   = (const float*)d_in[1];
    const float* W1   = (const float*)d_in[2];
    const float* W2   = (const float*)d_in[3];
    const int*   erow = (const int*)d_in[4];
    const int*   ecol = (const int*)d_in[5];
    float* out = (float*)d_out;

    // workspace layout (4B elements) — same as R13
    float* h      = (float*)d_ws;              // N*H1
    float* h2     = h  + (size_t)N_ * H1_;     // N*H2
    float* z      = h2 + (size_t)N_ * H2_;     // N*H2
    float* we     = z  + (size_t)N_ * H2_;     // N*CAP
    int*   cole   = (int*)(we + (size_t)N_ * CAP_);   // N*CAP
    int*   cursor = cole + (size_t)N_ * CAP_;  // N

    gemm_xw1_zero<<<GEMM_BLOCKS + ZERO_BLOCKS, 256, 0, stream>>>(x, W1, h, cursor);
    scatter_ell<<<(E_ + 255) / 256, 256, 0, stream>>>(erow, ecol, ew, cursor, cole, we);
    spmm1_mlp<<<(N_ + 7) / 8, 256, 0, stream>>>(h, cursor, cole, we, W2, h2);
    spmm2<<<(N_ + 15) / 16, 256, 0, stream>>>(h2, cursor, cole, we, z);

    dim3 grid((N_ + BJ - 1) / BJ, (N_ + BI - 1) / BI);   // 40 x 157
    zzt2x<<<grid, 256, 0, stream>>>(z, out);
}